// Round 1
// baseline (397.864 us; speedup 1.0000x reference)
//
#include <hip/hip_runtime.h>
#include <stdint.h>

#define M_TOT 8192
#define N_TOT 4096
#define K_TOT 4096

typedef __attribute__((ext_vector_type(8))) short bf16x8;
typedef __attribute__((ext_vector_type(4))) float f32x4;
typedef __attribute__((ext_vector_type(2))) unsigned short u16x2;
typedef __attribute__((ext_vector_type(4))) unsigned short u16x4;

typedef const __attribute__((address_space(1))) void* gas1;
typedef __attribute__((address_space(3))) void* las3;

__device__ __forceinline__ unsigned short bf16_rne(float f) {
    union { float f; unsigned int u; } v; v.f = f;
    unsigned int u = v.u;
    return (unsigned short)((u + 0x7FFFu + ((u >> 16) & 1u)) >> 16);
}

// Fake-quantize one weight to FP4(E2M1, group scale) and dequantize, exactly
// mirroring the reference's f32 math. The reference's round-half-even +
// clip behavior collapses to this comparison chain on a = |w|/scale:
//   a<=0.25 -> 0 ; (0.25,1) -> 0.5 ; [1,1.25] -> 1 ; (1.25,2) -> 1.5
//   [2,2.5] -> 2 ; (2.5,4) -> 3 ; [4,5] -> 4 ; >5 -> 6
__device__ __forceinline__ float fp4_qdq(float wv, float scale) {
    float a = fabsf(wv) / scale;
    float q;
    if      (a <= 0.25f) q = 0.0f;
    else if (a <  1.0f ) q = 0.5f;
    else if (a <= 1.25f) q = 1.0f;
    else if (a <  2.0f ) q = 1.5f;
    else if (a <= 2.5f ) q = 2.0f;
    else if (a <  4.0f ) q = 3.0f;
    else if (a <= 5.0f ) q = 4.0f;
    else                 q = 6.0f;
    float d = q * scale;
    return wv < 0.0f ? -d : d;
}

// One wave per group of 128 along K. 4096*4096/128 = 131072 groups.
__global__ __launch_bounds__(256) void quant_w_kernel(const float* __restrict__ w,
                                                      unsigned short* __restrict__ wb) {
    int gwave = blockIdx.x * 4 + (threadIdx.x >> 6);
    int lane = threadIdx.x & 63;
    size_t base = (size_t)gwave * 128;
    float2 v = ((const float2*)(w + base))[lane];
    float mx = fmaxf(fabsf(v.x), fabsf(v.y));
    #pragma unroll
    for (int off = 32; off; off >>= 1) mx = fmaxf(mx, __shfl_xor(mx, off));
    float scale = fmaxf(mx / 6.0f, 1e-8f);
    u16x2 o;
    o.x = bf16_rne(fp4_qdq(v.x, scale));
    o.y = bf16_rne(fp4_qdq(v.y, scale));
    *(u16x2*)(wb + base + (size_t)lane * 2) = o;
}

// x f32 -> bf16 (RNE), vectorized float4 -> ushort4.
__global__ __launch_bounds__(256) void cvt_x_kernel(const float* __restrict__ x,
                                                    unsigned short* __restrict__ xb) {
    const int total4 = (M_TOT * K_TOT) / 4;
    int stride = gridDim.x * blockDim.x;
    for (int i = blockIdx.x * blockDim.x + threadIdx.x; i < total4; i += stride) {
        float4 v = ((const float4*)x)[i];
        u16x4 o;
        o.x = bf16_rne(v.x); o.y = bf16_rne(v.y);
        o.z = bf16_rne(v.z); o.w = bf16_rne(v.w);
        ((u16x4*)xb)[i] = o;
    }
}

// C[m][n] = sum_k A[m][k]*B[n][k] + bias[n]; A,B bf16 K-contig, C f32.
// 128x128 tile, BK=64, 4 waves (2x2), 16x16x32 MFMA, global_load_lds staging
// with st-swizzle done on the global source (rule 21: linear LDS dest,
// inverse-swizzled source, swizzled ds_read).
__global__ __launch_bounds__(256) void gemm_kernel(const unsigned short* __restrict__ A,
                                                   const unsigned short* __restrict__ B,
                                                   const float* __restrict__ bias,
                                                   float* __restrict__ C) {
    __shared__ unsigned short lds_a[128 * 64];
    __shared__ unsigned short lds_b[128 * 64];

    int bid = blockIdx.x;
    // XCD-bijective swizzle: 2048 blocks = 8 XCDs * 256
    int s = ((bid & 7) << 8) | (bid >> 3);
    int tm = s >> 5;   // 64 M-tiles
    int tn = s & 31;   // 32 N-tiles
    int m0 = tm << 7, n0 = tn << 7;

    int t = threadIdx.x;
    int lane = t & 63;
    int wid = t >> 6;
    int wr = (wid >> 1) & 1, wc = wid & 1;

    f32x4 acc[4][4];
    #pragma unroll
    for (int i = 0; i < 4; ++i)
        #pragma unroll
        for (int j = 0; j < 4; ++j)
            acc[i][j] = (f32x4)0.0f;

    for (int k0 = 0; k0 < K_TOT; k0 += 64) {
        // stage 128x64 bf16 A and B tiles; granule sg writes LDS bytes [sg*16, sg*16+16)
        // physical row = sg>>3; source col (elems) = ((sg&7) ^ (row&7)) * 8  (inverse swizzle)
        #pragma unroll
        for (int i = 0; i < 4; ++i) {
            int sg = i * 256 + t;
            int row = sg >> 3;
            int col = ((sg ^ (sg >> 3)) & 7) << 3;
            const unsigned short* ga = A + (size_t)(m0 + row) * K_TOT + (size_t)(k0 + col);
            const unsigned short* gb = B + (size_t)(n0 + row) * K_TOT + (size_t)(k0 + col);
            __builtin_amdgcn_global_load_lds((gas1)ga, (las3)(lds_a + (size_t)sg * 8), 16, 0, 0);
            __builtin_amdgcn_global_load_lds((gas1)gb, (las3)(lds_b + (size_t)sg * 8), 16, 0, 0);
        }
        __syncthreads();

        #pragma unroll
        for (int kk = 0; kk < 2; ++kk) {
            bf16x8 af[4], bg[4];
            #pragma unroll
            for (int f = 0; f < 4; ++f) {
                int ra = (wr << 6) + (f << 4) + (lane & 15);
                int ca = ((kk << 6) | ((lane >> 4) << 4)) ^ ((ra & 7) << 4); // byte offset in row
                af[f] = *(const bf16x8*)(lds_a + ra * 64 + (ca >> 1));
                int rb = (wc << 6) + (f << 4) + (lane & 15);
                int cb = ((kk << 6) | ((lane >> 4) << 4)) ^ ((rb & 7) << 4);
                bg[f] = *(const bf16x8*)(lds_b + rb * 64 + (cb >> 1));
            }
            #pragma unroll
            for (int i = 0; i < 4; ++i)
                #pragma unroll
                for (int j = 0; j < 4; ++j)
                    acc[i][j] = __builtin_amdgcn_mfma_f32_16x16x32_bf16(af[i], bg[j], acc[i][j], 0, 0, 0);
        }
        __syncthreads();
    }

    // epilogue: C/D layout col=lane&15, row=(lane>>4)*4+reg
    #pragma unroll
    for (int j = 0; j < 4; ++j) {
        int n = n0 + (wc << 6) + (j << 4) + (lane & 15);
        float bv = bias[n];
        #pragma unroll
        for (int i = 0; i < 4; ++i) {
            int mb = m0 + (wr << 6) + (i << 4) + ((lane >> 4) << 2);
            #pragma unroll
            for (int r = 0; r < 4; ++r)
                C[(size_t)(mb + r) * N_TOT + n] = acc[i][j][r] + bv;
        }
    }
}

extern "C" void kernel_launch(void* const* d_in, const int* in_sizes, int n_in,
                              void* d_out, int out_size, void* d_ws, size_t ws_size,
                              hipStream_t stream) {
    const float* x    = (const float*)d_in[0];
    const float* w    = (const float*)d_in[1];
    const float* bias = (const float*)d_in[2];
    float* out = (float*)d_out;

    unsigned short* wb = (unsigned short*)d_ws;                      // 32 MiB
    unsigned short* xb = wb + (size_t)N_TOT * K_TOT;                 // +64 MiB

    quant_w_kernel<<<(N_TOT * K_TOT / 128) / 4, 256, 0, stream>>>(w, wb);
    cvt_x_kernel<<<2048, 256, 0, stream>>>(x, xb);
    gemm_kernel<<<2048, 256, 0, stream>>>(xb, wb, bias, out);
}

// Round 2
// 351.367 us; speedup vs baseline: 1.1323x; 1.1323x over previous
//
#include <hip/hip_runtime.h>
#include <stdint.h>

#define M_TOT 8192
#define N_TOT 4096
#define K_TOT 4096
#define NTILE 64   // K-tiles of BK=64

typedef __attribute__((ext_vector_type(8))) short bf16x8;
typedef __attribute__((ext_vector_type(4))) float f32x4;
typedef __attribute__((ext_vector_type(2))) unsigned short u16x2;
typedef __attribute__((ext_vector_type(4))) unsigned short u16x4;

typedef const __attribute__((address_space(1))) void* gas1;
typedef __attribute__((address_space(3))) void* las3;

__device__ __forceinline__ unsigned short bf16_rne(float f) {
    union { float f; unsigned int u; } v; v.f = f;
    unsigned int u = v.u;
    return (unsigned short)((u + 0x7FFFu + ((u >> 16) & 1u)) >> 16);
}

// Exact collapse of the reference FP4(E2M1) quant-dequant on a = |w|/scale.
__device__ __forceinline__ float fp4_qdq(float wv, float scale) {
    float a = fabsf(wv) / scale;
    float q;
    if      (a <= 0.25f) q = 0.0f;
    else if (a <  1.0f ) q = 0.5f;
    else if (a <= 1.25f) q = 1.0f;
    else if (a <  2.0f ) q = 1.5f;
    else if (a <= 2.5f ) q = 2.0f;
    else if (a <  4.0f ) q = 3.0f;
    else if (a <= 5.0f ) q = 4.0f;
    else                 q = 6.0f;
    float d = q * scale;
    return wv < 0.0f ? -d : d;
}

__global__ __launch_bounds__(256) void quant_w_kernel(const float* __restrict__ w,
                                                      unsigned short* __restrict__ wb) {
    int gwave = blockIdx.x * 4 + (threadIdx.x >> 6);
    int lane = threadIdx.x & 63;
    size_t base = (size_t)gwave * 128;
    float2 v = ((const float2*)(w + base))[lane];
    float mx = fmaxf(fabsf(v.x), fabsf(v.y));
    #pragma unroll
    for (int off = 32; off; off >>= 1) mx = fmaxf(mx, __shfl_xor(mx, off));
    float scale = fmaxf(mx / 6.0f, 1e-8f);
    u16x2 o;
    o.x = bf16_rne(fp4_qdq(v.x, scale));
    o.y = bf16_rne(fp4_qdq(v.y, scale));
    *(u16x2*)(wb + base + (size_t)lane * 2) = o;
}

__global__ __launch_bounds__(256) void cvt_x_kernel(const float* __restrict__ x,
                                                    unsigned short* __restrict__ xb) {
    const int total4 = (M_TOT * K_TOT) / 4;
    int stride = gridDim.x * blockDim.x;
    for (int i = blockIdx.x * blockDim.x + threadIdx.x; i < total4; i += stride) {
        float4 v = ((const float4*)x)[i];
        u16x4 o;
        o.x = bf16_rne(v.x); o.y = bf16_rne(v.y);
        o.z = bf16_rne(v.z); o.w = bf16_rne(v.w);
        ((u16x4*)xb)[i] = o;
    }
}

// ---------------- 256x256 8-phase GEMM (T2+T3+T4+T5) ----------------
// C[m][n] = sum_k A[m][k]*B[n][k] + bias[n]; A,B bf16 K-contig, C f32.
// 512 threads = 8 waves (2M x 4N). BK=64 split into k-halves of 32.
// LDS: 2 buffers x { A_k0, A_k1, B_k0, B_k1 } of [256 rows][32 cols] bf16 (16KB each).
// Rotation swizzle within 64B rows: LDS pos p holds source granule (p-(r>>1))&3.
// Counted vmcnt(10) at phases 2 and 4 of every K-tile; never 0 in the loop.

#define BAR()      __builtin_amdgcn_s_barrier()
#define SCHEDB()   __builtin_amdgcn_sched_barrier(0)
#define WAITLGKM() asm volatile("s_waitcnt lgkmcnt(0)" ::: "memory")
#define WAITVM10() asm volatile("s_waitcnt vmcnt(10)" ::: "memory")
#define WAITVM0()  asm volatile("s_waitcnt vmcnt(0)" ::: "memory")

__global__ __launch_bounds__(512) void gemm_kernel(const unsigned short* __restrict__ A,
                                                   const unsigned short* __restrict__ B,
                                                   const float* __restrict__ bias,
                                                   float* __restrict__ C) {
    extern __shared__ unsigned char lds[];   // 131072 bytes

    const int bid = blockIdx.x;
    const int sw = ((bid & 7) << 6) | (bid >> 3);   // XCD-contiguous chunks (512 % 8 == 0)
    const int tn = sw >> 5;    // 0..15
    const int tm = sw & 31;    // 0..31
    const int m0 = tm << 8, n0 = tn << 8;

    const int t = threadIdx.x;
    const int l = t & 63;
    const int wid = t >> 6;
    const int wr = wid >> 2;   // 0..1
    const int wc = wid & 3;    // 0..3
    const int l15 = l & 15;
    const int q4 = l >> 4;

    // Staging precompute: thread t covers granules G0=t and G1=512+t of each
    // 1024-granule region. Row r=G>>2, LDS pos p=G&3 holds source granule
    // s=(p-(r>>1))&3  (inverse of read-side p=(q+(r>>1))&3).
    const int r0g = t >> 2,        p0g = t & 3;
    const int r1g = (512 + t) >> 2, p1g = t & 3;
    const int s0g = (p0g - (r0g >> 1)) & 3;
    const int s1g = (p1g - (r1g >> 1)) & 3;
    const unsigned short* arow0 = A + (size_t)(m0 + r0g) * K_TOT + s0g * 8;
    const unsigned short* arow1 = A + (size_t)(m0 + r1g) * K_TOT + s1g * 8;
    const unsigned short* brow0 = B + (size_t)(n0 + r0g) * K_TOT + s0g * 8;
    const unsigned short* brow1 = B + (size_t)(n0 + r1g) * K_TOT + s1g * 8;
    const unsigned lo0 = (unsigned)t * 16u;
    const unsigned lo1 = lo0 + 8192u;

#define STAGE(ROW0, ROW1, MATOFF, KK, TT, BB) do {                                   \
      const unsigned _base = (unsigned)(BB) * 65536u + (MATOFF) + (KK) * 16384u;     \
      const int _ko = (TT) * 64 + (KK) * 32;                                         \
      __builtin_amdgcn_global_load_lds((gas1)(ROW0 + _ko), (las3)(lds + _base + lo0), 16, 0, 0); \
      __builtin_amdgcn_global_load_lds((gas1)(ROW1 + _ko), (las3)(lds + _base + lo1), 16, 0, 0); \
    } while (0)
#define STAGE_A(KK, TT, BB) STAGE(arow0, arow1, 0u, KK, TT, BB)
#define STAGE_B(KK, TT, BB) STAGE(brow0, brow1, 32768u, KK, TT, BB)

#define LOAD_A(QM, KK, BB) do {                                                      \
      _Pragma("unroll")                                                              \
      for (int i = 0; i < 4; ++i) {                                                  \
        int ra = wr * 128 + (QM) * 64 + i * 16 + l15;                                \
        unsigned pa = (unsigned)((q4 + (ra >> 1)) & 3);                              \
        af[i] = *(const bf16x8*)(lds + (unsigned)(BB) * 65536u + (KK) * 16384u       \
                                 + (unsigned)ra * 64u + pa * 16u);                   \
      } } while (0)

#define LOAD_B(KK, BB) do {                                                          \
      _Pragma("unroll")                                                              \
      for (int n = 0; n < 4; ++n) {                                                  \
        int rb = wc * 64 + n * 16 + l15;                                             \
        unsigned pb = (unsigned)((q4 + (rb >> 1)) & 3);                              \
        bg[n] = *(const bf16x8*)(lds + (unsigned)(BB) * 65536u + 32768u              \
                                 + (KK) * 16384u + (unsigned)rb * 64u + pb * 16u);   \
      } } while (0)

#define MFMA16(QM) do {                                                              \
      _Pragma("unroll")                                                              \
      for (int i = 0; i < 4; ++i)                                                    \
        _Pragma("unroll")                                                            \
        for (int n = 0; n < 4; ++n)                                                  \
          acc[(QM) * 4 + i][n] = __builtin_amdgcn_mfma_f32_16x16x32_bf16(            \
              af[i], bg[n], acc[(QM) * 4 + i][n], 0, 0, 0);                          \
    } while (0)

// One K-tile = 4 phases. Region free/issue/deadline schedule hand-verified:
// ph1 reads Ak0,Bk0; issues Ak1(u+1)->buf^1. ph2 reads Ak0; issues Bk0(u+2); vmcnt(10).
// ph3 reads Ak1,Bk1; issues Ak0(u+2). ph4 reads Ak1; issues Bk1(u+2); vmcnt(10).
#define KTILE(U, BB) do {                                                            \
      const int tt1 = ((U) + 1 < NTILE) ? (U) + 1 : (U) - 1;                         \
      const int tt2 = ((U) + 2 < NTILE) ? (U) + 2 : (U);                             \
      /* phase 1: kk=0 qm=0 */                                                       \
      LOAD_B(0, BB); LOAD_A(0, 0, BB);                                               \
      STAGE_A(1, tt1, 1 - (BB));                                                     \
      BAR(); WAITLGKM(); SCHEDB();                                                   \
      __builtin_amdgcn_s_setprio(1); MFMA16(0); __builtin_amdgcn_s_setprio(0);       \
      BAR(); SCHEDB();                                                               \
      /* phase 2: kk=0 qm=1 */                                                       \
      LOAD_A(1, 0, BB);                                                              \
      STAGE_B(0, tt2, BB);                                                           \
      BAR(); WAITLGKM(); SCHEDB();                                                   \
      __builtin_amdgcn_s_setprio(1); MFMA16(1); __builtin_amdgcn_s_setprio(0);       \
      WAITVM10(); BAR(); SCHEDB();                                                   \
      /* phase 3: kk=1 qm=0 */                                                       \
      LOAD_B(1, BB); LOAD_A(0, 1, BB);                                               \
      STAGE_A(0, tt2, BB);                                                           \
      BAR(); WAITLGKM(); SCHEDB();                                                   \
      __builtin_amdgcn_s_setprio(1); MFMA16(0); __builtin_amdgcn_s_setprio(0);       \
      BAR(); SCHEDB();                                                               \
      /* phase 4: kk=1 qm=1 */                                                       \
      LOAD_A(1, 1, BB);                                                              \
      STAGE_B(1, tt2, BB);                                                           \
      BAR(); WAITLGKM(); SCHEDB();                                                   \
      __builtin_amdgcn_s_setprio(1); MFMA16(1); __builtin_amdgcn_s_setprio(0);       \
      WAITVM10(); BAR(); SCHEDB();                                                   \
    } while (0)

    f32x4 acc[8][4];
    #pragma unroll
    for (int i = 0; i < 8; ++i)
        #pragma unroll
        for (int j = 0; j < 4; ++j)
            acc[i][j] = (f32x4)0.0f;
    bf16x8 af[4], bg[4];

    // Prologue: tile0 {Ak0,Bk0,Ak1,Bk1}, tile1 {Ak0,Bk0,Bk1} (Ak1(1) issued in ph1 of u=0).
    STAGE_A(0, 0, 0); STAGE_B(0, 0, 0); STAGE_A(1, 0, 0); STAGE_B(1, 0, 0);
    STAGE_A(0, 1, 1); STAGE_B(0, 1, 1); STAGE_B(1, 1, 1);
    WAITVM10();   // 14 issued, completes >= 4: Ak0(0), Bk0(0)
    BAR(); SCHEDB();

    #pragma unroll 1
    for (int u = 0; u < NTILE; u += 2) {
        KTILE(u, 0);
        KTILE(u + 1, 1);
    }
    WAITVM0();   // drain idempotent tail reloads before LDS dealloc

    // Epilogue: C/D layout col=lane&15, row=(lane>>4)*4+reg
    #pragma unroll
    for (int j = 0; j < 4; ++j) {
        int n = n0 + wc * 64 + j * 16 + l15;
        float bv = bias[n];
        #pragma unroll
        for (int i = 0; i < 8; ++i) {
            int mb = m0 + wr * 128 + i * 16 + (q4 << 2);
            #pragma unroll
            for (int r = 0; r < 4; ++r)
                C[(size_t)(mb + r) * N_TOT + n] = acc[i][j][r] + bv;
        }
    }
}

extern "C" void kernel_launch(void* const* d_in, const int* in_sizes, int n_in,
                              void* d_out, int out_size, void* d_ws, size_t ws_size,
                              hipStream_t stream) {
    const float* x    = (const float*)d_in[0];
    const float* w    = (const float*)d_in[1];
    const float* bias = (const float*)d_in[2];
    float* out = (float*)d_out;

    unsigned short* wb = (unsigned short*)d_ws;                      // 32 MiB
    unsigned short* xb = wb + (size_t)N_TOT * K_TOT;                 // +64 MiB

    quant_w_kernel<<<(N_TOT * K_TOT / 128) / 4, 256, 0, stream>>>(w, wb);
    cvt_x_kernel<<<2048, 256, 0, stream>>>(x, xb);

    hipFuncSetAttribute(reinterpret_cast<const void*>(gemm_kernel),
                        hipFuncAttributeMaxDynamicSharedMemorySize, 131072);
    gemm_kernel<<<512, 512, 131072, stream>>>(xb, wb, bias, out);
}

// Round 3
// 298.599 us; speedup vs baseline: 1.3324x; 1.1767x over previous
//
#include <hip/hip_runtime.h>
#include <stdint.h>

#define M_TOT 8192
#define N_TOT 4096
#define K_TOT 4096
#define NTILE 64   // K-tiles of BK=64

typedef __attribute__((ext_vector_type(8))) short bf16x8;
typedef __attribute__((ext_vector_type(4))) float f32x4;
typedef __attribute__((ext_vector_type(2))) unsigned short u16x2;
typedef __attribute__((ext_vector_type(4))) unsigned short u16x4;

typedef const __attribute__((address_space(1))) void* gas1;
typedef __attribute__((address_space(3))) void* las3;

__device__ __forceinline__ unsigned short bf16_rne(float f) {
    union { float f; unsigned int u; } v; v.f = f;
    unsigned int u = v.u;
    return (unsigned short)((u + 0x7FFFu + ((u >> 16) & 1u)) >> 16);
}

// Exact collapse of the reference FP4(E2M1) quant-dequant on a = |w|/scale.
__device__ __forceinline__ float fp4_qdq(float wv, float scale) {
    float a = fabsf(wv) / scale;
    float q;
    if      (a <= 0.25f) q = 0.0f;
    else if (a <  1.0f ) q = 0.5f;
    else if (a <= 1.25f) q = 1.0f;
    else if (a <  2.0f ) q = 1.5f;
    else if (a <= 2.5f ) q = 2.0f;
    else if (a <  4.0f ) q = 3.0f;
    else if (a <= 5.0f ) q = 4.0f;
    else                 q = 6.0f;
    float d = q * scale;
    return wv < 0.0f ? -d : d;
}

__global__ __launch_bounds__(256) void quant_w_kernel(const float* __restrict__ w,
                                                      unsigned short* __restrict__ wb) {
    int gwave = blockIdx.x * 4 + (threadIdx.x >> 6);
    int lane = threadIdx.x & 63;
    size_t base = (size_t)gwave * 128;
    float2 v = ((const float2*)(w + base))[lane];
    float mx = fmaxf(fabsf(v.x), fabsf(v.y));
    #pragma unroll
    for (int off = 32; off; off >>= 1) mx = fmaxf(mx, __shfl_xor(mx, off));
    float scale = fmaxf(mx / 6.0f, 1e-8f);
    u16x2 o;
    o.x = bf16_rne(fp4_qdq(v.x, scale));
    o.y = bf16_rne(fp4_qdq(v.y, scale));
    *(u16x2*)(wb + base + (size_t)lane * 2) = o;
}

__global__ __launch_bounds__(256) void cvt_x_kernel(const float* __restrict__ x,
                                                    unsigned short* __restrict__ xb) {
    const int total4 = (M_TOT * K_TOT) / 4;
    int stride = gridDim.x * blockDim.x;
    for (int i = blockIdx.x * blockDim.x + threadIdx.x; i < total4; i += stride) {
        float4 v = ((const float4*)x)[i];
        u16x4 o;
        o.x = bf16_rne(v.x); o.y = bf16_rne(v.y);
        o.z = bf16_rne(v.z); o.w = bf16_rne(v.w);
        ((u16x4*)xb)[i] = o;
    }
}

// ---------------- 256x256 8-phase GEMM (T2+T3+T4+T5) ----------------
// C[m][n] = sum_k A[m][k]*B[n][k] + bias[n]; A,B bf16 K-contig, C f32.
// 512 threads = 8 waves (2M x 4N). BK=64 split into k-halves of 32.
// LDS: 2 buffers x { A_k0, A_k1, B_k0, B_k1 } of [256 rows][32 cols] bf16 (16KB each).
// Rotation swizzle within 64B rows: LDS pos p holds source granule (p-(r>>1))&3.
// Single counted vmcnt(6) per K-tile (end of phase 4); never 0 in the loop.

#define BAR()      __builtin_amdgcn_s_barrier()
#define SCHEDB()   __builtin_amdgcn_sched_barrier(0)
#define WAITLGKM() asm volatile("s_waitcnt lgkmcnt(0)" ::: "memory")
#define WAITVM6()  asm volatile("s_waitcnt vmcnt(6)" ::: "memory")
#define WAITVM0()  asm volatile("s_waitcnt vmcnt(0)" ::: "memory")

__global__ __launch_bounds__(512) void gemm_kernel(const unsigned short* __restrict__ A,
                                                   const unsigned short* __restrict__ B,
                                                   const float* __restrict__ bias,
                                                   float* __restrict__ C) {
    extern __shared__ unsigned char lds[];   // 131072 bytes

    // 2D-chunked XCD swizzle: XCD = bid&7 owns a 16tm x 4tn rectangle;
    // within it, the 32 concurrently-resident blocks (idx 0..31) cover
    // 8tm x 4tn -> per-K-step L2 working set = 12 panels x 32KB = 384KB << 4MB.
    const int bid = blockIdx.x;
    const int xcd = bid & 7;
    const int idx = bid >> 3;          // 0..63
    const int tm = ((xcd >> 2) << 4) + (idx >> 2);   // 0..31
    const int tn = ((xcd & 3) << 2) + (idx & 3);     // 0..15
    const int m0 = tm << 8, n0 = tn << 8;

    const int t = threadIdx.x;
    const int l = t & 63;
    const int wid = t >> 6;
    const int wr = wid >> 2;   // 0..1
    const int wc = wid & 3;    // 0..3
    const int l15 = l & 15;
    const int q4 = l >> 4;

    // Staging precompute: thread t covers granules G0=t and G1=512+t of each
    // 1024-granule region. Row r=G>>2, LDS pos p=G&3 holds source granule
    // s=(p-(r>>1))&3  (inverse of read-side p=(q+(r>>1))&3).
    const int r0g = t >> 2,        p0g = t & 3;
    const int r1g = (512 + t) >> 2, p1g = t & 3;
    const int s0g = (p0g - (r0g >> 1)) & 3;
    const int s1g = (p1g - (r1g >> 1)) & 3;
    const unsigned short* arow0 = A + (size_t)(m0 + r0g) * K_TOT + s0g * 8;
    const unsigned short* arow1 = A + (size_t)(m0 + r1g) * K_TOT + s1g * 8;
    const unsigned short* brow0 = B + (size_t)(n0 + r0g) * K_TOT + s0g * 8;
    const unsigned short* brow1 = B + (size_t)(n0 + r1g) * K_TOT + s1g * 8;
    const unsigned lo0 = (unsigned)t * 16u;
    const unsigned lo1 = lo0 + 8192u;

#define STAGE(ROW0, ROW1, MATOFF, KK, TT, BB) do {                                   \
      const unsigned _base = (unsigned)(BB) * 65536u + (MATOFF) + (KK) * 16384u;     \
      const int _ko = (TT) * 64 + (KK) * 32;                                         \
      __builtin_amdgcn_global_load_lds((gas1)(ROW0 + _ko), (las3)(lds + _base + lo0), 16, 0, 0); \
      __builtin_amdgcn_global_load_lds((gas1)(ROW1 + _ko), (las3)(lds + _base + lo1), 16, 0, 0); \
    } while (0)
#define STAGE_A(KK, TT, BB) STAGE(arow0, arow1, 0u, KK, TT, BB)
#define STAGE_B(KK, TT, BB) STAGE(brow0, brow1, 32768u, KK, TT, BB)

#define LOAD_A(QM, KK, BB) do {                                                      \
      _Pragma("unroll")                                                              \
      for (int i = 0; i < 4; ++i) {                                                  \
        int ra = wr * 128 + (QM) * 64 + i * 16 + l15;                                \
        unsigned pa = (unsigned)((q4 + (ra >> 1)) & 3);                              \
        af[i] = *(const bf16x8*)(lds + (unsigned)(BB) * 65536u + (KK) * 16384u       \
                                 + (unsigned)ra * 64u + pa * 16u);                   \
      } } while (0)

#define LOAD_B(KK, BB) do {                                                          \
      _Pragma("unroll")                                                              \
      for (int n = 0; n < 4; ++n) {                                                  \
        int rb = wc * 64 + n * 16 + l15;                                             \
        unsigned pb = (unsigned)((q4 + (rb >> 1)) & 3);                              \
        bg[n] = *(const bf16x8*)(lds + (unsigned)(BB) * 65536u + 32768u              \
                                 + (KK) * 16384u + (unsigned)rb * 64u + pb * 16u);   \
      } } while (0)

#define MFMA16(QM) do {                                                              \
      _Pragma("unroll")                                                              \
      for (int i = 0; i < 4; ++i)                                                    \
        _Pragma("unroll")                                                            \
        for (int n = 0; n < 4; ++n)                                                  \
          acc[(QM) * 4 + i][n] = __builtin_amdgcn_mfma_f32_16x16x32_bf16(            \
              af[i], bg[n], acc[(QM) * 4 + i][n], 0, 0, 0);                          \
    } while (0)

// One K-tile = 4 phases.
// ph1 reads Ak0,Bk0; issues Ak1(u+1)->buf^1. ph2 reads Ak0; issues Bk0(u+2).
// ph3 reads Ak1,Bk1; issues Ak0(u+2). ph4 reads Ak1; issues Bk1(u+2); vmcnt(6).
// vmcnt(6) at end of ph4 covers everything tile u+1 reads (latest-needed =
// Ak1(u+1), staged at u-ph1; exactly 6 load-instrs issue after it).
#define KTILE(U, BB) do {                                                            \
      const int tt1 = ((U) + 1 < NTILE) ? (U) + 1 : (U) - 1;                         \
      const int tt2 = ((U) + 2 < NTILE) ? (U) + 2 : (U);                             \
      /* phase 1: kk=0 qm=0 */                                                       \
      LOAD_B(0, BB); LOAD_A(0, 0, BB);                                               \
      STAGE_A(1, tt1, 1 - (BB));                                                     \
      BAR(); WAITLGKM(); SCHEDB();                                                   \
      __builtin_amdgcn_s_setprio(1); MFMA16(0); __builtin_amdgcn_s_setprio(0);       \
      BAR(); SCHEDB();                                                               \
      /* phase 2: kk=0 qm=1 */                                                       \
      LOAD_A(1, 0, BB);                                                              \
      STAGE_B(0, tt2, BB);                                                           \
      BAR(); WAITLGKM(); SCHEDB();                                                   \
      __builtin_amdgcn_s_setprio(1); MFMA16(1); __builtin_amdgcn_s_setprio(0);       \
      BAR(); SCHEDB();                                                               \
      /* phase 3: kk=1 qm=0 */                                                       \
      LOAD_B(1, BB); LOAD_A(0, 1, BB);                                               \
      STAGE_A(0, tt2, BB);                                                           \
      BAR(); WAITLGKM(); SCHEDB();                                                   \
      __builtin_amdgcn_s_setprio(1); MFMA16(0); __builtin_amdgcn_s_setprio(0);       \
      BAR(); SCHEDB();                                                               \
      /* phase 4: kk=1 qm=1 */                                                       \
      LOAD_A(1, 1, BB);                                                              \
      STAGE_B(1, tt2, BB);                                                           \
      BAR(); WAITLGKM(); SCHEDB();                                                   \
      __builtin_amdgcn_s_setprio(1); MFMA16(1); __builtin_amdgcn_s_setprio(0);       \
      WAITVM6(); BAR(); SCHEDB();                                                    \
    } while (0)

    f32x4 acc[8][4];
    #pragma unroll
    for (int i = 0; i < 8; ++i)
        #pragma unroll
        for (int j = 0; j < 4; ++j)
            acc[i][j] = (f32x4)0.0f;
    bf16x8 af[4], bg[4];

    // Prologue: tile0 {Ak0,Bk0,Ak1,Bk1}, tile1 {Ak0,Bk0,Bk1} (Ak1(1) issued in ph1 of u=0).
    // 14 load-instrs issued; need first 8 (all of tile 0) done -> vmcnt(6).
    STAGE_A(0, 0, 0); STAGE_B(0, 0, 0); STAGE_A(1, 0, 0); STAGE_B(1, 0, 0);
    STAGE_A(0, 1, 1); STAGE_B(0, 1, 1); STAGE_B(1, 1, 1);
    WAITVM6();
    BAR(); SCHEDB();

    #pragma unroll 1
    for (int u = 0; u < NTILE; u += 2) {
        KTILE(u, 0);
        KTILE(u + 1, 1);
    }
    WAITVM0();   // drain idempotent tail reloads before LDS dealloc

    // Epilogue: C/D layout col=lane&15, row=(lane>>4)*4+reg
    #pragma unroll
    for (int j = 0; j < 4; ++j) {
        int n = n0 + wc * 64 + j * 16 + l15;
        float bv = bias[n];
        #pragma unroll
        for (int i = 0; i < 8; ++i) {
            int mb = m0 + wr * 128 + i * 16 + (q4 << 2);
            #pragma unroll
            for (int r = 0; r < 4; ++r)
                C[(size_t)(mb + r) * N_TOT + n] = acc[i][j][r] + bv;
        }
    }
}

extern "C" void kernel_launch(void* const* d_in, const int* in_sizes, int n_in,
                              void* d_out, int out_size, void* d_ws, size_t ws_size,
                              hipStream_t stream) {
    const float* x    = (const float*)d_in[0];
    const float* w    = (const float*)d_in[1];
    const float* bias = (const float*)d_in[2];
    float* out = (float*)d_out;

    unsigned short* wb = (unsigned short*)d_ws;                      // 32 MiB
    unsigned short* xb = wb + (size_t)N_TOT * K_TOT;                 // +64 MiB

    quant_w_kernel<<<(N_TOT * K_TOT / 128) / 4, 256, 0, stream>>>(w, wb);
    cvt_x_kernel<<<2048, 256, 0, stream>>>(x, xb);

    hipFuncSetAttribute(reinterpret_cast<const void*>(gemm_kernel),
                        hipFuncAttributeMaxDynamicSharedMemorySize, 131072);
    gemm_kernel<<<512, 512, 131072, stream>>>(xb, wb, bias, out);
}